// Round 1
// baseline (763.302 us; speedup 1.0000x reference)
//
#include <hip/hip_runtime.h>
#include <stdint.h>

typedef __bf16 bf16;
typedef __bf16 bf16x8 __attribute__((ext_vector_type(8)));
typedef __bf16 bf16x4 __attribute__((ext_vector_type(4)));
typedef float  f32x4  __attribute__((ext_vector_type(4)));

#define AS1 __attribute__((address_space(1)))
#define AS3 __attribute__((address_space(3)))

// async global->LDS, 16B per lane; l must be wave-uniform (HW adds lane*16)
__device__ __forceinline__ void gload16(void* l, const void* g) {
  __builtin_amdgcn_global_load_lds((AS1 void*)(g), (AS3 void*)(l), 16, 0, 0);
}

#define NB 4
#define TT 2048
#define CC 1024
#define HH 16
#define DD 64
#define DHID 4096
#define MM (NB*TT)   // 8192

// ---------------- weight fp32 -> bf16 convert ----------------
// dst layout: [wq 1M | wk 1M | wv 1M | fc1 4M | fc2 4M] bf16 elems
__global__ __launch_bounds__(256)
void cvt_kernel(const float* __restrict__ wq, const float* __restrict__ wk,
                const float* __restrict__ wvv, const float* __restrict__ f1,
                const float* __restrict__ f2, bf16* __restrict__ dst) {
  const int NCH = 2883584;  // 11,534,336 elems / 4
  for (int ch = blockIdx.x*256 + threadIdx.x; ch < NCH; ch += gridDim.x*256) {
    const float* s; int base;
    if (ch < 262144)       { s = wq;  base = 0; }
    else if (ch < 524288)  { s = wk;  base = 262144; }
    else if (ch < 786432)  { s = wvv; base = 524288; }
    else if (ch < 1835008) { s = f1;  base = 786432; }
    else                   { s = f2;  base = 1835008; }
    float4 v = ((const float4*)s)[ch - base];
    bf16x4 o = { (bf16)v.x, (bf16)v.y, (bf16)v.z, (bf16)v.w };
    *(bf16x4*)(dst + (size_t)ch*4) = o;
  }
}

// ---------------- fused layernorm -> bf16 ----------------
__global__ __launch_bounds__(256)
void ln_kernel(const float* __restrict__ x, const float* __restrict__ w,
               const float* __restrict__ b, bf16* __restrict__ out) {
  const int row = blockIdx.x;
  const int t = threadIdx.x;
  const float4 v = ((const float4*)(x + (size_t)row*CC))[t];
  float s  = v.x + v.y + v.z + v.w;
  float sq = v.x*v.x + v.y*v.y + v.z*v.z + v.w*v.w;
  #pragma unroll
  for (int m = 1; m < 64; m <<= 1) {
    s  += __shfl_xor(s, m, 64);
    sq += __shfl_xor(sq, m, 64);
  }
  __shared__ float red[8];
  const int wv = t >> 6;
  if ((t & 63) == 0) { red[wv] = s; red[4+wv] = sq; }
  __syncthreads();
  s  = red[0]+red[1]+red[2]+red[3];
  sq = red[4]+red[5]+red[6]+red[7];
  const float mu = s * (1.0f/CC);
  const float rs = rsqrtf(sq*(1.0f/CC) - mu*mu + 1e-5f);
  const float4 wv4 = ((const float4*)w)[t];
  const float4 bv4 = ((const float4*)b)[t];
  bf16x4 o = { (bf16)((v.x-mu)*rs*wv4.x + bv4.x),
               (bf16)((v.y-mu)*rs*wv4.y + bv4.y),
               (bf16)((v.z-mu)*rs*wv4.z + bv4.z),
               (bf16)((v.w-mu)*rs*wv4.w + bv4.w) };
  *(bf16x4*)(out + (size_t)row*CC + t*4) = o;
}

__device__ __forceinline__ float gelu_f(float x) {
  const float kC = 0.7978845608028654f;
  float z = kC * (x + 0.044715f * x*x*x);
  float e = __expf(2.0f*z);            // e->inf ok: 2/(inf+1)=0
  float th = 1.0f - 2.0f/(e + 1.0f);
  return 0.5f * x * (1.0f + th);
}

// ---------------- GEMM: C[M,N] = A[M,K] @ B[N,K]^T, bf16 in, f32 acc ----------------
// MODE 0: QKV -> scatter bf16 to q/k/v [n,h,t,d] (outp = qkv base, N=3072)
// MODE 1: gelu(acc + bias) -> bf16 row-major [M,4096]
// MODE 2: acc + bias + resid -> fp32 row-major [M,1024]
template<int MODE>
__global__ __launch_bounds__(256)
void gemm_kernel(const bf16* __restrict__ A, const bf16* __restrict__ B, int K,
                 void* outp, const float* __restrict__ bias, const float* resid) {
  __shared__ __align__(16) bf16 Ab[128*32];
  __shared__ __align__(16) bf16 Bb[128*32];
  const int tid  = threadIdx.x;
  const int lane = tid & 63;
  const int wv   = tid >> 6;
  const int g = lane >> 4, c = lane & 15;
  const int bm0 = blockIdx.x * 128;
  const int bn0 = blockIdx.y * 128;
  const int wm = (wv >> 1) * 64, wn = (wv & 1) * 64;

  f32x4 acc[4][4] = {};

  // staging: 512 chunks of 16B per tile; thread handles chunk tid and tid+256
  const int r0 = tid >> 2, c8 = tid & 3;          // rows 0..63
  const bf16* a0 = A + (size_t)(bm0 + r0)     * K + c8*8;
  const bf16* a1 = A + (size_t)(bm0 + r0 + 64)* K + c8*8;
  const bf16* b0 = B + (size_t)(bn0 + r0)     * K + c8*8;
  const bf16* b1 = B + (size_t)(bn0 + r0 + 64)* K + c8*8;
  bf16* alds0 = &Ab[wv*512];
  bf16* alds1 = &Ab[(4+wv)*512];
  bf16* blds0 = &Bb[wv*512];
  bf16* blds1 = &Bb[(4+wv)*512];

  for (int kt = 0; kt < K; kt += 32) {
    gload16(alds0, a0 + kt);
    gload16(alds1, a1 + kt);
    gload16(blds0, b0 + kt);
    gload16(blds1, b1 + kt);
    asm volatile("s_waitcnt vmcnt(0)" ::: "memory");
    __syncthreads();
    bf16x8 af[4], bfv[4];
    #pragma unroll
    for (int ms = 0; ms < 4; ++ms)
      af[ms] = *(const bf16x8*)&Ab[(wm + ms*16 + c)*32 + g*8];
    #pragma unroll
    for (int ns = 0; ns < 4; ++ns)
      bfv[ns] = *(const bf16x8*)&Bb[(wn + ns*16 + c)*32 + g*8];
    #pragma unroll
    for (int ms = 0; ms < 4; ++ms) {
      #pragma unroll
      for (int ns = 0; ns < 4; ++ns)
        acc[ms][ns] = __builtin_amdgcn_mfma_f32_16x16x32_bf16(af[ms], bfv[ns], acc[ms][ns], 0, 0, 0);
    }
    __syncthreads();
  }

  // epilogue: D layout col = lane&15, row = (lane>>4)*4 + reg
  #pragma unroll
  for (int ms = 0; ms < 4; ++ms) {
    const int m = bm0 + wm + ms*16 + g*4;   // +jj
    #pragma unroll
    for (int ns = 0; ns < 4; ++ns) {
      const int j = bn0 + wn + ns*16 + c;
      if constexpr (MODE == 0) {
        const int which = j >> 10, hd = j & 1023;
        const int n_ = m >> 11, t_ = m & 2047;
        bf16* dst = (bf16*)outp + (size_t)which*(MM*CC)
                    + (((size_t)(n_*HH + (hd>>6))*TT + t_) << 6) + (hd & 63);
        #pragma unroll
        for (int jj = 0; jj < 4; ++jj)
          dst[(size_t)jj << 6] = (bf16)acc[ms][ns][jj];
      } else if constexpr (MODE == 1) {
        const float bb = bias[j];
        bf16* o = (bf16*)outp;
        #pragma unroll
        for (int jj = 0; jj < 4; ++jj)
          o[(size_t)(m+jj)*DHID + j] = (bf16)gelu_f(acc[ms][ns][jj] + bb);
      } else {
        const float bb = bias[j];
        float* o = (float*)outp;
        #pragma unroll
        for (int jj = 0; jj < 4; ++jj) {
          const size_t ix = (size_t)(m+jj)*CC + j;
          o[ix] = acc[ms][ns][jj] + bb + resid[ix];
        }
      }
    }
  }
}

// ---------------- flash attention (causal) + residual add ----------------
// q/k/v bf16 [n,h,t,64]; out[n,t,1024] = x + softmax(QK^T/8, causal) V
__global__ __launch_bounds__(256)
void attn_kernel(const bf16* __restrict__ qkv, const float* __restrict__ x,
                 float* __restrict__ out) {
  __shared__ __align__(16) bf16 Kb[32*64];
  __shared__ __align__(16) bf16 Vb[32*64];
  __shared__ __align__(16) bf16 Pb[4][32*48];  // per-wave, 96B rows
  const int tid = threadIdx.x, lane = tid & 63, wv = tid >> 6;
  const int g = lane >> 4, c = lane & 15;
  const int nh = blockIdx.x >> 4, qb = blockIdx.x & 15;
  const int n = nh >> 4, h = nh & 15;
  const bf16* qp = qkv + (size_t)nh * (TT*DD);
  const bf16* kp = qp + (size_t)MM*CC;
  const bf16* vp = qp + (size_t)2*MM*CC;
  const int q0 = qb*128 + wv*32;

  // Q fragments (A operand): row = lane&15, k = (lane>>4)*8+j
  bf16x8 qf[2][2];
  #pragma unroll
  for (int ms = 0; ms < 2; ++ms) {
    #pragma unroll
    for (int kk = 0; kk < 2; ++kk)
      qf[ms][kk] = *(const bf16x8*)(qp + (size_t)(q0 + ms*16 + c)*DD + kk*32 + g*8);
  }

  f32x4 o[2][4] = {};
  float mrow[2][4], lrow[2][4];
  #pragma unroll
  for (int ms = 0; ms < 2; ++ms) {
    #pragma unroll
    for (int jj = 0; jj < 4; ++jj) { mrow[ms][jj] = -3e38f; lrow[ms][jj] = 0.f; }
  }

  const int wdiag = q0 >> 5;         // this wave's diagonal key-tile
  const int ktend = qb*4 + 4;        // block stages up to max wave's range
  const int krow = tid >> 3, kc8 = tid & 7;

  for (int kt = 0; kt < ktend; ++kt) {
    // K tile: global_load_lds, XOR-pre-swizzled source (chunk ^= row&7)
    gload16(&Kb[wv*512], kp + (size_t)(kt*32 + krow)*DD + ((kc8 ^ (krow & 7)) << 3));
    // V tile: reg-stage, store at col ^ ((row>>3)<<4)
    bf16x8 vvec = *(const bf16x8*)(vp + (size_t)(kt*32 + krow)*DD + kc8*8);
    *(bf16x8*)&Vb[krow*64 + ((kc8*8) ^ ((krow >> 3) << 4))] = vvec;
    asm volatile("s_waitcnt vmcnt(0)" ::: "memory");
    __syncthreads();

    if (kt <= wdiag) {
      f32x4 s4[2][2] = {};
      #pragma unroll
      for (int ks = 0; ks < 2; ++ks) {
        const int key = ks*16 + c;
        #pragma unroll
        for (int kk = 0; kk < 2; ++kk) {
          bf16x8 kf = *(const bf16x8*)&Kb[key*64 + ((((kk << 2) | g) ^ (c & 7)) << 3)];
          #pragma unroll
          for (int ms = 0; ms < 2; ++ms)
            s4[ms][ks] = __builtin_amdgcn_mfma_f32_16x16x32_bf16(qf[ms][kk], kf, s4[ms][ks], 0, 0, 0);
        }
      }
      const bool diag = (kt == wdiag);
      #pragma unroll
      for (int ms = 0; ms < 2; ++ms) {
        #pragma unroll
        for (int ks = 0; ks < 2; ++ks) {
          #pragma unroll
          for (int jj = 0; jj < 4; ++jj) {
            float sv = s4[ms][ks][jj] * 0.125f;
            if (diag) {
              const int key = kt*32 + ks*16 + c;
              const int qg  = q0 + ms*16 + g*4 + jj;
              if (key > qg) sv = -1e30f;
            }
            s4[ms][ks][jj] = sv;
          }
        }
      }
      // online softmax per q-row (row = g*4+jj within 16)
      #pragma unroll
      for (int ms = 0; ms < 2; ++ms) {
        #pragma unroll
        for (int jj = 0; jj < 4; ++jj) {
          float tm = fmaxf(s4[ms][0][jj], s4[ms][1][jj]);
          tm = fmaxf(tm, __shfl_xor(tm, 1, 64));
          tm = fmaxf(tm, __shfl_xor(tm, 2, 64));
          tm = fmaxf(tm, __shfl_xor(tm, 4, 64));
          tm = fmaxf(tm, __shfl_xor(tm, 8, 64));
          const float mo = mrow[ms][jj];
          const float mn = fmaxf(mo, tm);
          const float sc = __expf(mo - mn);
          mrow[ms][jj] = mn;
          const float p0 = __expf(s4[ms][0][jj] - mn);
          const float p1 = __expf(s4[ms][1][jj] - mn);
          float rs = p0 + p1;
          rs += __shfl_xor(rs, 1, 64);
          rs += __shfl_xor(rs, 2, 64);
          rs += __shfl_xor(rs, 4, 64);
          rs += __shfl_xor(rs, 8, 64);
          lrow[ms][jj] = lrow[ms][jj]*sc + rs;
          #pragma unroll
          for (int ds = 0; ds < 4; ++ds) o[ms][ds][jj] *= sc;
          const int prow = ms*16 + g*4 + jj;
          Pb[wv][prow*48 + c]      = (bf16)p0;
          Pb[wv][prow*48 + 16 + c] = (bf16)p1;
        }
      }
      asm volatile("s_waitcnt lgkmcnt(0)" ::: "memory");
      // PV: A = P (rows=q), B = V (col=d, strided reads, swizzled conflict-free)
      #pragma unroll
      for (int ms = 0; ms < 2; ++ms) {
        bf16x8 pa = *(const bf16x8*)&Pb[wv][(ms*16 + c)*48 + g*8];
        #pragma unroll
        for (int ds = 0; ds < 4; ++ds) {
          const int colx = (ds*16 + c) ^ (g << 4);
          bf16x8 vb;
          #pragma unroll
          for (int j = 0; j < 8; ++j)
            vb[j] = Vb[(g*8 + j)*64 + colx];
          o[ms][ds] = __builtin_amdgcn_mfma_f32_16x16x32_bf16(pa, vb, o[ms][ds], 0, 0, 0);
        }
      }
    }
    __syncthreads();
  }

  // epilogue: out = x + O / l
  #pragma unroll
  for (int ms = 0; ms < 2; ++ms) {
    #pragma unroll
    for (int jj = 0; jj < 4; ++jj) {
      const float inv = 1.0f / lrow[ms][jj];
      const int qg = q0 + ms*16 + g*4 + jj;
      #pragma unroll
      for (int ds = 0; ds < 4; ++ds) {
        const size_t ix = ((size_t)n*TT + qg)*CC + h*DD + ds*16 + c;
        out[ix] = x[ix] + o[ms][ds][jj]*inv;
      }
    }
  }
}

// ---------------- launcher ----------------
extern "C" void kernel_launch(void* const* d_in, const int* in_sizes, int n_in,
                              void* d_out, int out_size, void* d_ws, size_t ws_size,
                              hipStream_t stream) {
  const float* x    = (const float*)d_in[0];
  const float* ln1w = (const float*)d_in[1];
  const float* ln1b = (const float*)d_in[2];
  const float* wq   = (const float*)d_in[3];
  const float* wk   = (const float*)d_in[4];
  const float* wvv  = (const float*)d_in[5];
  const float* ln2w = (const float*)d_in[6];
  const float* ln2b = (const float*)d_in[7];
  const float* f1w  = (const float*)d_in[8];
  const float* f1b  = (const float*)d_in[9];
  const float* f2w  = (const float*)d_in[10];
  const float* f2b  = (const float*)d_in[11];
  float* out = (float*)d_out;

  bf16* ws     = (bf16*)d_ws;
  bf16* wfused = ws;                   // [wq|wk|wv] = B for QKV gemm (3072x1024)
  bf16* wf1    = ws + 3145728;         // fc1 (4096x1024)
  bf16* wf2    = ws + 7340032;         // fc2 (1024x4096)
  bf16* lnb    = ws + 11534336;        // ln output, 8192x1024
  bf16* big    = ws + 19922944;        // qkv [3][n,h,t,d] (24M) then h1 (32M)
  bf16* h1     = big;

  cvt_kernel<<<2048, 256, 0, stream>>>(wq, wk, wvv, f1w, f2w, wfused);
  ln_kernel<<<MM, 256, 0, stream>>>(x, ln1w, ln1b, lnb);
  gemm_kernel<0><<<dim3(64, 24), 256, 0, stream>>>(lnb, wfused, 1024, big, nullptr, nullptr);
  attn_kernel<<<1024, 256, 0, stream>>>(big, x, out);
  ln_kernel<<<MM, 256, 0, stream>>>(out, ln2w, ln2b, lnb);
  gemm_kernel<1><<<dim3(64, 32), 256, 0, stream>>>(lnb, wf1, 1024, h1, f1b, nullptr);
  gemm_kernel<2><<<dim3(64, 8), 256, 0, stream>>>(h1, wf2, 4096, out, f2b, out);
}

// Round 6
// 508.923 us; speedup vs baseline: 1.4998x; 1.4998x over previous
//
#include <hip/hip_runtime.h>
#include <stdint.h>

typedef __bf16 bf16;
typedef __bf16 bf16x8 __attribute__((ext_vector_type(8)));
typedef __bf16 bf16x4 __attribute__((ext_vector_type(4)));
typedef float  f32x4  __attribute__((ext_vector_type(4)));

#define AS1 __attribute__((address_space(1)))
#define AS3 __attribute__((address_space(3)))

// async global->LDS, 16B per lane; LDS dest is wave-uniform base + lane*16B
__device__ __forceinline__ void gload16(void* l, const void* g) {
  __builtin_amdgcn_global_load_lds((AS1 void*)(g), (AS3 void*)(l), 16, 0, 0);
}

#define NB 4
#define TT 2048
#define CC 1024
#define HH 16
#define DD 64
#define DHID 4096
#define MM (NB*TT)   // 8192

// ---------------- weight fp32 -> bf16 convert ----------------
__global__ __launch_bounds__(256)
void cvt_kernel(const float* __restrict__ wq, const float* __restrict__ wk,
                const float* __restrict__ wvv, const float* __restrict__ f1,
                const float* __restrict__ f2, bf16* __restrict__ dst) {
  const int NCH = 2883584;  // 11,534,336 elems / 4
  for (int ch = blockIdx.x*256 + threadIdx.x; ch < NCH; ch += gridDim.x*256) {
    const float* s; int base;
    if (ch < 262144)       { s = wq;  base = 0; }
    else if (ch < 524288)  { s = wk;  base = 262144; }
    else if (ch < 786432)  { s = wvv; base = 524288; }
    else if (ch < 1835008) { s = f1;  base = 786432; }
    else                   { s = f2;  base = 1835008; }
    float4 v = ((const float4*)s)[ch - base];
    bf16x4 o = { (bf16)v.x, (bf16)v.y, (bf16)v.z, (bf16)v.w };
    *(bf16x4*)(dst + (size_t)ch*4) = o;
  }
}

// ---------------- fused layernorm -> bf16 ----------------
__global__ __launch_bounds__(256)
void ln_kernel(const float* __restrict__ x, const float* __restrict__ w,
               const float* __restrict__ b, bf16* __restrict__ out) {
  const int row = blockIdx.x;
  const int t = threadIdx.x;
  const float4 v = ((const float4*)(x + (size_t)row*CC))[t];
  float s  = v.x + v.y + v.z + v.w;
  float sq = v.x*v.x + v.y*v.y + v.z*v.z + v.w*v.w;
  #pragma unroll
  for (int m = 1; m < 64; m <<= 1) {
    s  += __shfl_xor(s, m, 64);
    sq += __shfl_xor(sq, m, 64);
  }
  __shared__ float red[8];
  const int wv = t >> 6;
  if ((t & 63) == 0) { red[wv] = s; red[4+wv] = sq; }
  __syncthreads();
  s  = red[0]+red[1]+red[2]+red[3];
  sq = red[4]+red[5]+red[6]+red[7];
  const float mu = s * (1.0f/CC);
  const float rs = rsqrtf(sq*(1.0f/CC) - mu*mu + 1e-5f);
  const float4 wv4 = ((const float4*)w)[t];
  const float4 bv4 = ((const float4*)b)[t];
  bf16x4 o = { (bf16)((v.x-mu)*rs*wv4.x + bv4.x),
               (bf16)((v.y-mu)*rs*wv4.y + bv4.y),
               (bf16)((v.z-mu)*rs*wv4.z + bv4.z),
               (bf16)((v.w-mu)*rs*wv4.w + bv4.w) };
  *(bf16x4*)(out + (size_t)row*CC + t*4) = o;
}

__device__ __forceinline__ float gelu_f(float x) {
  const float kC = 0.7978845608028654f;
  float z = kC * (x + 0.044715f * x*x*x);
  float e = __expf(2.0f*z);
  float th = 1.0f - 2.0f/(e + 1.0f);
  return 0.5f * x * (1.0f + th);
}

// ---------------- GEMM: C[M,N] = A[M,K] @ B[N,K]^T, 2-phase prefetch ----------------
template<int MODE>
__global__ __launch_bounds__(256)
void gemm_kernel(const bf16* __restrict__ A, const bf16* __restrict__ B, int K,
                 void* outp, const float* __restrict__ bias, const float* resid) {
  __shared__ __align__(16) bf16 Ab[2][128*32];
  __shared__ __align__(16) bf16 Bb[2][128*32];
  const int tid  = threadIdx.x;
  const int lane = tid & 63;
  const int wv   = tid >> 6;
  const int g = lane >> 4, c = lane & 15;
  const int bm0 = blockIdx.x * 128;
  const int bn0 = blockIdx.y * 128;
  const int wm = (wv >> 1) * 64, wn = (wv & 1) * 64;

  f32x4 acc[4][4] = {};

  const int r0 = tid >> 2, c8 = tid & 3;
  const bf16* a0 = A + (size_t)(bm0 + r0)     * K + c8*8;
  const bf16* a1 = A + (size_t)(bm0 + r0 + 64)* K + c8*8;
  const bf16* b0 = B + (size_t)(bn0 + r0)     * K + c8*8;
  const bf16* b1 = B + (size_t)(bn0 + r0 + 64)* K + c8*8;

  #define GSTAGE(buf, kk)                                   \
    do {                                                    \
      gload16(&Ab[buf][wv*512],     a0 + (kk));             \
      gload16(&Ab[buf][(4+wv)*512], a1 + (kk));             \
      gload16(&Bb[buf][wv*512],     b0 + (kk));             \
      gload16(&Bb[buf][(4+wv)*512], b1 + (kk));             \
    } while (0)

  GSTAGE(0, 0);
  asm volatile("s_waitcnt vmcnt(0)" ::: "memory");
  __syncthreads();

  int cur = 0;
  for (int kt = 0; kt < K; kt += 32) {
    if (kt + 32 < K) GSTAGE(cur ^ 1, kt + 32);
    bf16x8 af[4], bfv[4];
    #pragma unroll
    for (int ms = 0; ms < 4; ++ms)
      af[ms] = *(const bf16x8*)&Ab[cur][(wm + ms*16 + c)*32 + g*8];
    #pragma unroll
    for (int ns = 0; ns < 4; ++ns)
      bfv[ns] = *(const bf16x8*)&Bb[cur][(wn + ns*16 + c)*32 + g*8];
    #pragma unroll
    for (int ms = 0; ms < 4; ++ms) {
      #pragma unroll
      for (int ns = 0; ns < 4; ++ns)
        acc[ms][ns] = __builtin_amdgcn_mfma_f32_16x16x32_bf16(af[ms], bfv[ns], acc[ms][ns], 0, 0, 0);
    }
    asm volatile("s_waitcnt vmcnt(0)" ::: "memory");
    __syncthreads();
    cur ^= 1;
  }

  // epilogue: D layout col = lane&15, row = (lane>>4)*4 + reg
  #pragma unroll
  for (int ms = 0; ms < 4; ++ms) {
    const int m = bm0 + wm + ms*16 + g*4;
    #pragma unroll
    for (int ns = 0; ns < 4; ++ns) {
      const int j = bn0 + wn + ns*16 + c;
      if constexpr (MODE == 0) {
        const int which = j >> 10, hd = j & 1023;
        const int n_ = m >> 11, t_ = m & 2047;
        bf16* dst = (bf16*)outp + (size_t)which*(MM*CC)
                    + (((size_t)(n_*HH + (hd>>6))*TT + t_) << 6) + (hd & 63);
        #pragma unroll
        for (int jj = 0; jj < 4; ++jj)
          dst[(size_t)jj << 6] = (bf16)acc[ms][ns][jj];
      } else if constexpr (MODE == 1) {
        const float bb = bias[j];
        bf16* o = (bf16*)outp;
        #pragma unroll
        for (int jj = 0; jj < 4; ++jj)
          o[(size_t)(m+jj)*DHID + j] = (bf16)gelu_f(acc[ms][ns][jj] + bb);
      } else {
        const float bb = bias[j];
        float* o = (float*)outp;
        #pragma unroll
        for (int jj = 0; jj < 4; ++jj) {
          const size_t ix = (size_t)(m+jj)*CC + j;
          o[ix] = acc[ms][ns][jj] + bb + resid[ix];
        }
      }
    }
  }
  #undef GSTAGE
}

// ---------------- flash attention (causal, swapped-QK^T) + residual ----------------
// Block: 256 thr (4 waves), head nh, q-tile pair {pr, 15-pr} (128 rows each,
// 32/wave). KBLK=64. S^T via mfma(K,Q); O^T via mfma(Vt, P). One barrier/tile.
__global__ __launch_bounds__(256)
void attn_kernel(const bf16* __restrict__ qkv, const float* __restrict__ x,
                 float* __restrict__ out) {
  __shared__ __align__(16) bf16 Kb[2][64*64];   // [key][d], chunk^=(key&7)
  __shared__ __align__(16) bf16 Vt[2][64*64];   // [d][key], chunk^=(d&7)^((d>>4)<<1)
  __shared__ __align__(16) bf16 Pb[4][32*64];   // per-wave [q][key], chunk^=(q&7)
  const int tid = threadIdx.x, lane = tid & 63, wv = tid >> 6;
  const int g = lane >> 4, c = lane & 15;
  const int nh = blockIdx.x >> 3, pr = blockIdx.x & 7;
  const int n = nh >> 4, h = nh & 15;
  const bf16* qp = qkv + (size_t)nh * (TT*DD);
  const bf16* kp = qp + (size_t)(MM*CC);
  const bf16* vp = qp + (size_t)(2*MM*CC);
  const float INVS = 0.125f * 1.4426950408889634f;  // 1/sqrt(64) * log2(e)

  // K staging: 2 chunks/thread; dest = base + lane*16B (rows krow0, krow1)
  const int krow0 = wv*8 + (lane >> 3), kch = lane & 7;
  const int krow1 = krow0 + 32;
  const int ksw0 = ((kch ^ (krow0 & 7)) << 3);
  const int ksw1 = ((kch ^ (krow1 & 7)) << 3);
  // V staging: thread loads V[key][qd*16..+15], writes transposed
  const int vkey = tid >> 2, vqd = tid & 3;

  #define VT_WRITE(buf)                                                      \
    do {                                                                     \
      _Pragma("unroll")                                                      \
      for (int j2 = 0; j2 < 16; ++j2) {                                      \
        const int d = vqd*16 + j2;                                           \
        const int ch = ((vkey >> 3) ^ (j2 & 7) ^ (vqd << 1)) & 7;            \
        Vt[buf][d*64 + (ch << 3) + (vkey & 7)] =                             \
            (j2 < 8) ? vr0[j2] : vr1[j2 - 8];                                \
      }                                                                      \
    } while (0)

  for (int half = 0; half < 2; ++half) {
    const int qt = half ? (15 - pr) : pr;
    const int q0w = qt*128 + wv*32;
    const int ktl = (q0w + 31) >> 6;   // this wave's last (diag) k-tile
    const int nkt = 2*qt + 2;          // block iteration count

    // Q fragments (B operand): col=q=qs*16+c, k=d=kk*32+g*8+j
    bf16x8 qf[2][2];
    #pragma unroll
    for (int qs = 0; qs < 2; ++qs)
      #pragma unroll
      for (int kk = 0; kk < 2; ++kk)
        qf[qs][kk] = *(const bf16x8*)(qp + (size_t)(q0w + qs*16 + c)*DD + kk*32 + g*8);

    f32x4 o[2][4] = {};
    float mrow[2] = {-1e30f, -1e30f};
    float lrow[2] = {0.f, 0.f};

    // ---- prologue: stage tile 0 ----
    gload16(&Kb[0][wv*512],        kp + (size_t)krow0*DD + ksw0);
    gload16(&Kb[0][2048 + wv*512], kp + (size_t)krow1*DD + ksw1);
    bf16x8 vr0 = *(const bf16x8*)(vp + (size_t)vkey*DD + vqd*16);
    bf16x8 vr1 = *(const bf16x8*)(vp + (size_t)vkey*DD + vqd*16 + 8);
    asm volatile("s_waitcnt vmcnt(0)" ::: "memory");
    VT_WRITE(0);
    __syncthreads();

    int cur = 0;
    for (int kt = 0; kt < nkt; ++kt) {
      const int nxt = cur ^ 1;
      const bool hn = (kt + 1) < nkt;
      if (hn) {
        const size_t kb = (size_t)(kt + 1) * 64;
        gload16(&Kb[nxt][wv*512],        kp + (kb + krow0)*DD + ksw0);
        gload16(&Kb[nxt][2048 + wv*512], kp + (kb + krow1)*DD + ksw1);
        vr0 = *(const bf16x8*)(vp + (kb + vkey)*DD + vqd*16);
        vr1 = *(const bf16x8*)(vp + (kb + vkey)*DD + vqd*16 + 8);
        asm volatile("" :: "v"(vr0), "v"(vr1));   // keep loads issued early
      }

      if (kt <= ktl) {
        // ---- QK^T (S^T tiles): A=K, B=Q ----
        f32x4 sa[4][2] = {};
        #pragma unroll
        for (int ks = 0; ks < 4; ++ks) {
          #pragma unroll
          for (int kk = 0; kk < 2; ++kk) {
            const bf16x8 kf = *(const bf16x8*)
                &Kb[cur][(ks*16 + c)*64 + (((kk*4 + g) ^ (c & 7)) << 3)];
            #pragma unroll
            for (int qs = 0; qs < 2; ++qs)
              sa[ks][qs] = __builtin_amdgcn_mfma_f32_16x16x32_bf16(
                  kf, qf[qs][kk], sa[ks][qs], 0, 0, 0);
          }
        }
        const bool diag = (kt == ktl);
        // ---- online softmax: lane owns q=qs*16+c, 16 keys; cross-g = 2 shfl ----
        #pragma unroll
        for (int qs = 0; qs < 2; ++qs) {
          const int q = q0w + qs*16 + c;
          float p[4][4];
          #pragma unroll
          for (int ks = 0; ks < 4; ++ks)
            #pragma unroll
            for (int jj = 0; jj < 4; ++jj) {
              float sv = sa[ks][qs][jj] * INVS;
              if (diag && (kt*64 + ks*16 + g*4 + jj > q)) sv = -1e30f;
              p[ks][jj] = sv;
            }
          float tm = p[0][0];
          #pragma unroll
          for (int ks = 0; ks < 4; ++ks)
            #pragma unroll
            for (int jj = 0; jj < 4; ++jj) tm = fmaxf(tm, p[ks][jj]);
          tm = fmaxf(tm, __shfl_xor(tm, 16, 64));
          tm = fmaxf(tm, __shfl_xor(tm, 32, 64));
          const float mo = mrow[qs];
          const float mn = fmaxf(mo, tm);
          const float sc = exp2f(mo - mn);
          mrow[qs] = mn;
          float rs = 0.f;
          #pragma unroll
          for (int ks = 0; ks < 4; ++ks)
            #pragma unroll
            for (int jj = 0; jj < 4; ++jj) {
              p[ks][jj] = exp2f(p[ks][jj] - mn);
              rs += p[ks][jj];
            }
          rs += __shfl_xor(rs, 16, 64);
          rs += __shfl_xor(rs, 32, 64);
          lrow[qs] = lrow[qs]*sc + rs;
          #pragma unroll
          for (int dt = 0; dt < 4; ++dt) o[qs][dt] *= sc;
          // P write: keys ks*16+g*4+{0..3} -> chunk (ks*2+(g>>1))^(q&7), sub (g&1)*4
          #pragma unroll
          for (int ks = 0; ks < 4; ++ks) {
            bf16x4 pw = { (bf16)p[ks][0], (bf16)p[ks][1],
                          (bf16)p[ks][2], (bf16)p[ks][3] };
            *(bf16x4*)&Pb[wv][(qs*16 + c)*64 +
                (((ks*2 + (g >> 1)) ^ (c & 7)) << 3) + ((g & 1) << 2)] = pw;
          }
        }
        asm volatile("s_waitcnt lgkmcnt(0)" ::: "memory");
        __builtin_amdgcn_sched_barrier(0);
        // ---- PV (O^T): A=Vt, B=P ----
        bf16x8 pbf[2][2];
        #pragma unroll
        for (int qs = 0; qs < 2; ++qs)
          #pragma unroll
          for (int kk = 0; kk < 2; ++kk)
            pbf[qs][kk] = *(const bf16x8*)
                &Pb[wv][(qs*16 + c)*64 + (((kk*4 + g) ^ (c & 7)) << 3)];
        #pragma unroll
        for (int dt = 0; dt < 4; ++dt) {
          #pragma unroll
          for (int kk = 0; kk < 2; ++kk) {
            const bf16x8 va = *(const bf16x8*)
                &Vt[cur][(dt*16 + c)*64 +
                         ((((kk*4 + g) ^ (c & 7) ^ (dt << 1)) & 7) << 3)];
            #pragma unroll
            for (int qs = 0; qs < 2; ++qs)
              o[qs][dt] = __builtin_amdgcn_mfma_f32_16x16x32_bf16(
                  va, pbf[qs][kk], o[qs][dt], 0, 0, 0);
          }
        }
      }

      asm volatile("s_waitcnt vmcnt(0)" ::: "memory");
      if (hn) VT_WRITE(nxt);
      __syncthreads();
      cur = nxt;
    }

    // ---- epilogue: out = x + O^T/l ; lane: q=qs*16+c, d=dt*16+g*4+jj ----
    #pragma unroll
    for (int qs = 0; qs < 2; ++qs) {
      const float inv = 1.0f / lrow[qs];
      const int q = q0w + qs*16 + c;
      #pragma unroll
      for (int dt = 0; dt < 4; ++dt) {
        const size_t base = ((size_t)n*TT + q)*CC + h*DD + dt*16 + g*4;
        const float4 xv = *(const float4*)(x + base);
        float4 ov;
        ov.x = xv.x + o[qs][dt][0]*inv;
        ov.y = xv.y + o[qs][dt][1]*inv;
        ov.z = xv.z + o[qs][dt][2]*inv;
        ov.w = xv.w + o[qs][dt][3]*inv;
        *(float4*)(out + base) = ov;
      }
    }
  }
  #undef VT_WRITE
}

// ---------------- launcher ----------------
extern "C" void kernel_launch(void* const* d_in, const int* in_sizes, int n_in,
                              void* d_out, int out_size, void* d_ws, size_t ws_size,
                              hipStream_t stream) {
  const float* x    = (const float*)d_in[0];
  const float* ln1w = (const float*)d_in[1];
  const float* ln1b = (const float*)d_in[2];
  const float* wq   = (const float*)d_in[3];
  const float* wk   = (const float*)d_in[4];
  const float* wvv  = (const float*)d_in[5];
  const float* ln2w = (const float*)d_in[6];
  const float* ln2b = (const float*)d_in[7];
  const float* f1w  = (const float*)d_in[8];
  const float* f1b  = (const float*)d_in[9];
  const float* f2w  = (const float*)d_in[10];
  const float* f2b  = (const float*)d_in[11];
  float* out = (float*)d_out;

  bf16* ws     = (bf16*)d_ws;
  bf16* wfused = ws;                   // [wq|wk|wv] (3072x1024)
  bf16* wf1    = ws + 3145728;         // fc1 (4096x1024)
  bf16* wf2    = ws + 7340032;         // fc2 (1024x4096)
  bf16* lnb    = ws + 11534336;        // ln output (8192x1024)
  bf16* big    = ws + 19922944;        // qkv [3][n,h,t,d] then h1
  bf16* h1     = big;

  cvt_kernel<<<2048, 256, 0, stream>>>(wq, wk, wvv, f1w, f2w, wfused);
  ln_kernel<<<MM, 256, 0, stream>>>(x, ln1w, ln1b, lnb);
  gemm_kernel<0><<<dim3(64, 24), 256, 0, stream>>>(lnb, wfused, 1024, big, nullptr, nullptr);
  attn_kernel<<<512, 256, 0, stream>>>(big, x, out);
  ln_kernel<<<MM, 256, 0, stream>>>(out, ln2w, ln2b, lnb);
  gemm_kernel<1><<<dim3(64, 32), 256, 0, stream>>>(lnb, wf1, 1024, h1, f1b, nullptr);
  gemm_kernel<2><<<dim3(64, 8), 256, 0, stream>>>(h1, wf2, 4096, out, f2b, out);
}